// Round 13
// baseline (390.674 us; speedup 1.0000x reference)
//
#include <hip/hip_runtime.h>
#include <stdint.h>

#define B_ROWS 4096
#define L_FEAT 256
#define VOCAB  8192
#define FRAG   1024             // one MFMA operand fragment: 32 rows x 64 elems
#define KCHUNKS (VOCAB / 64)    // 128 fragments along K per 32-row group
#define GBYTES  (KCHUNKS * FRAG)  // 128 KB per 32-row group
#define NSTEP  128              // K steps of 64 elems

typedef __attribute__((ext_vector_type(4)))  int   intx4;
typedef __attribute__((ext_vector_type(8)))  int   intx8;
typedef __attribute__((ext_vector_type(4)))  float floatx4;
typedef __attribute__((ext_vector_type(16))) float floatx16;

// fp4 operand: HW reads only v[0:3] of the 8-reg A/B field (FMT=4); upper
// half undef (verified r9-r12: passed, absmax 0).
__device__ __forceinline__ intx8 widen(intx4 v) {
  return __builtin_shufflevector(v, v, 0, 1, 2, 3, -1, -1, -1, -1);
}

// ---------------- kernel 1: presence in PANEL (MFMA-fragment) layout ---------
// (verified rounds 10-12) fragment (g,kc) holds rows [32g,32g+32) x k-elems
// [64kc,64kc+64), byte = (g*128+kc)*1024 + ((row&31)+32*half)*16.
__global__ __launch_bounds__(256) void presence_kernel(
    const int* __restrict__ f,
    uint32_t* __restrict__ P,     // fp4 presence, panel layout (16 MB)
    float* __restrict__ sizes) {
  __shared__ uint32_t rw[4][VOCAB / 8];   // 4 x 1024 words = 16 KB
  const int rbase = blockIdx.x * 4;
  const int tid = threadIdx.x;

  uint4* rp4 = (uint4*)&rw[0][0];         // 1024 uint4
  const uint4 z = make_uint4(0u, 0u, 0u, 0u);
  #pragma unroll
  for (int j = 0; j < 4; ++j) rp4[tid + j * 256] = z;
  __syncthreads();

  #pragma unroll
  for (int r = 0; r < 4; ++r) {
    const int v = f[(rbase + r) * L_FEAT + tid];     // coalesced
    atomicOr(&rw[r][v >> 3], 0x2u << ((v & 7) * 4)); // fp4 nibble 1.0; dups ok
  }
  __syncthreads();

  // panel write: 1024 chunks of 16B; chunk c -> kc=c>>3, half=(c>>2)&1, ro=c&3
  const int g = blockIdx.x >> 3;
  const int slotBase = (blockIdx.x & 7) * 4;   // row slot within 32-row group
  char* Pg = (char*)P + (size_t)g * GBYTES;
  #pragma unroll
  for (int j = 0; j < 4; ++j) {
    const int c  = tid + j * 256;
    const int kc = c >> 3, h = (c >> 2) & 1, ro = c & 3;
    const uint4 val = *(const uint4*)&rw[ro][kc * 8 + h * 4];
    *(uint4*)(Pg + kc * FRAG + (slotBase + ro + 32 * h) * 16) = val;
  }

  // sizes: wave w popcounts row w
  const int w = tid >> 6, lane = tid & 63;
  const uint4* sp4 = (const uint4*)&rw[w][0];        // 256 uint4
  int cnt = 0;
  #pragma unroll
  for (int q = 0; q < 4; ++q) {
    const uint4 x = sp4[lane + q * 64];
    cnt += __popc(x.x & 0x22222222u) + __popc(x.y & 0x22222222u) +
           __popc(x.z & 0x22222222u) + __popc(x.w & 0x22222222u);
  }
  #pragma unroll
  for (int off = 32; off > 0; off >>= 1) cnt += __shfl_down(cnt, off);
  if (lane == 0) sizes[rbase + w] = (float)cnt;
}

// ---------------- kernel 2: inter = P·P^T (fp4 MX MFMA) + Jaccard + mirror ---
// Round-13 = round-11 (verified) + K-PHASED EXECUTION:
//   r10/r11/r12 all hit a ~10.5-11 TB/s delivery ceiling on 1.06 GB of
//   operand demand (per-XCD working set 16 MB >> 4 MB L2 -> L3/fabric tier).
//   Fix: blocks on physical XCD x (raw blockIdx%8, HW round-robin) start the
//   K-loop at fragment 16*x and wrap mod 128. At any instant one XCD's blocks
//   read the SAME rotating K-slice of P: 4096 groups x 1 KB = 2 MB < 4 MB L2
//   -> operands served from L2 (34.5 TB/s), L3/HBM traffic = 8 x 16 MB
//   compulsory stream. Wrong %8 mapping degrades to r11, never below.
//   Everything else (panel layout, reg ring-8, supertile decode, epilogue)
//   unchanged from r11.
__global__ __launch_bounds__(256, 2) void gemm_kernel(
    const unsigned char* __restrict__ P,
    const float* __restrict__ sizes,
    float* __restrict__ out) {
  // K-phase by PHYSICAL XCD (raw blockIdx, before any swizzle)
  const int kstart = (blockIdx.x & 7) * 16 * FRAG;   // 16 frags per K-slice

  // XCD swizzle (528 = 8*66 -> bijective)
  int bid = blockIdx.x;
  bid = (bid & 7) * 66 + (bid >> 3);
  // supertile-triangle decode: 8x8 supertiles of 4x4 blocks, bx >= by
  int b = bid, sy = 0, rem = 122;               // 10 + 16*7
  while (b >= rem) { b -= rem; ++sy; rem -= 16; }
  int by, bx;
  if (b < 10) {                                 // diagonal supertile interior
    int ly = 0, r2 = 4;
    while (b >= r2) { b -= r2; ++ly; --r2; }
    by = sy * 4 + ly; bx = sy * 4 + ly + b;
  } else {
    const int t = b - 10;
    const int sx = sy + 1 + (t >> 4);
    const int l = t & 15;
    by = sy * 4 + (l >> 2); bx = sx * 4 + (l & 3);
  }

  const int tid  = threadIdx.x;
  const int wave = tid >> 6, lane = tid & 63;
  const int wm = wave >> 1, wn = wave & 1;   // 2x2 wave grid, each wave 64x64
  const int r31 = lane & 31, khalf = lane >> 5;

  const int iB = by * 128 + wm * 64;   // this wave's output rows
  const int jB = bx * 128 + wn * 64;   // this wave's output cols

  // fragment base pointers, phase-offset by kstart (wrap handled in loop)
  const unsigned char* pA0 =
      P + (size_t)(by * 4 + wm * 2 + 0) * GBYTES + kstart + lane * 16;
  const unsigned char* pA1 =
      P + (size_t)(by * 4 + wm * 2 + 1) * GBYTES + kstart + lane * 16;
  const unsigned char* pB0 =
      P + (size_t)(bx * 4 + wn * 2 + 0) * GBYTES + kstart + lane * 16;
  const unsigned char* pB1 =
      P + (size_t)(bx * 4 + wn * 2 + 1) * GBYTES + kstart + lane * 16;

  floatx16 acc[2][2];
  #pragma unroll
  for (int ai = 0; ai < 2; ++ai)
    #pragma unroll
    for (int ci = 0; ci < 2; ++ci)
      #pragma unroll
      for (int e = 0; e < 16; ++e) acc[ai][ci][e] = 0.f;

  intx4 a0[8], a1[8], b0[8], b1[8];   // 8-step register ring, literal indices

  #pragma unroll
  for (int j = 0; j < 8; ++j) {       // prologue: phase-steps 0..7
    a0[j] = *(const intx4*)(pA0 + j * FRAG);
    a1[j] = *(const intx4*)(pA1 + j * FRAG);
    b0[j] = *(const intx4*)(pB0 + j * FRAG);
    b1[j] = *(const intx4*)(pB1 + j * FRAG);
  }
  pA0 += 8 * FRAG; pA1 += 8 * FRAG; pB0 += 8 * FRAG; pB1 += 8 * FRAG;
  int kb = kstart + 8 * FRAG;   // max 114688+8192 < GBYTES: no wrap yet

  #define STEP(j)                                                             \
    {                                                                         \
      const intx8 A0 = widen(a0[j]), A1 = widen(a1[j]);                       \
      const intx8 B0 = widen(b0[j]), B1 = widen(b1[j]);                       \
      acc[0][0] = __builtin_amdgcn_mfma_scale_f32_32x32x64_f8f6f4(            \
          A0, B0, acc[0][0], 4, 4, 0, 127, 0, 127);                           \
      acc[0][1] = __builtin_amdgcn_mfma_scale_f32_32x32x64_f8f6f4(            \
          A0, B1, acc[0][1], 4, 4, 0, 127, 0, 127);                           \
      acc[1][0] = __builtin_amdgcn_mfma_scale_f32_32x32x64_f8f6f4(            \
          A1, B0, acc[1][0], 4, 4, 0, 127, 0, 127);                           \
      acc[1][1] = __builtin_amdgcn_mfma_scale_f32_32x32x64_f8f6f4(            \
          A1, B1, acc[1][1], 4, 4, 0, 127, 0, 127);                           \
    }
  #define PREF(j)                                                             \
    {                                                                         \
      a0[j] = *(const intx4*)(pA0 + (j) * FRAG);                              \
      a1[j] = *(const intx4*)(pA1 + (j) * FRAG);                              \
      b0[j] = *(const intx4*)(pB0 + (j) * FRAG);                              \
      b1[j] = *(const intx4*)(pB1 + (j) * FRAG);                              \
    }

  // 15 bodies x 8 steps; kstart and body stride are multiples of 8 frags, so
  // the mod-128 wrap always lands exactly on a body boundary (never mid-body).
  for (int i = 0; i < 15; ++i) {
    STEP(0) PREF(0)
    STEP(1) PREF(1)
    STEP(2) PREF(2)
    STEP(3) PREF(3)
    STEP(4) PREF(4)
    STEP(5) PREF(5)
    STEP(6) PREF(6)
    STEP(7) PREF(7)
    pA0 += 8 * FRAG; pA1 += 8 * FRAG; pB0 += 8 * FRAG; pB1 += 8 * FRAG;
    kb += 8 * FRAG;
    if (kb >= GBYTES) {               // wrap to K-fragment 0 (once per kernel)
      kb -= GBYTES;
      pA0 -= GBYTES; pA1 -= GBYTES; pB0 -= GBYTES; pB1 -= GBYTES;
    }
  }
  STEP(0) STEP(1) STEP(2) STEP(3)     // last 8 phase-steps
  STEP(4) STEP(5) STEP(6) STEP(7)

  // epilogue (verified rounds 5-12): sim = -inter/(|A_i|+|A_j|-inter) + mirror.
  // 32x32 C layout: col = lane&31, row = (reg&3) + 8*(reg>>2) + 4*(lane>>5).
  #pragma unroll
  for (int tm = 0; tm < 2; ++tm) {
    const int rowb = iB + tm * 32 + 4 * khalf;
    #pragma unroll
    for (int tn = 0; tn < 2; ++tn) {
      const int colb = jB + tn * 32 + r31;
      const float sj = sizes[colb];
      #pragma unroll
      for (int q = 0; q < 4; ++q) {           // reg quads: rows rq..rq+3
        const int rq = rowb + 8 * q;
        floatx4 tv;
        #pragma unroll
        for (int j = 0; j < 4; ++j) {
          const float inter = acc[tm][tn][4 * q + j];
          const float u = sizes[rq + j] + sj - inter;
          tv[j] = (u != 0.f) ? (-inter / u) : 0.f;
        }
        __builtin_nontemporal_store(tv[0], &out[(size_t)(rq + 0) * B_ROWS + colb]);
        __builtin_nontemporal_store(tv[1], &out[(size_t)(rq + 1) * B_ROWS + colb]);
        __builtin_nontemporal_store(tv[2], &out[(size_t)(rq + 2) * B_ROWS + colb]);
        __builtin_nontemporal_store(tv[3], &out[(size_t)(rq + 3) * B_ROWS + colb]);
        // mirrored: 4 row-values contiguous in the transposed row (16B-aligned)
        __builtin_nontemporal_store(tv, (floatx4*)&out[(size_t)colb * B_ROWS + rq]);
      }
    }
  }
}

// ---------------- launcher ---------------------------------------------------
extern "C" void kernel_launch(void* const* d_in, const int* in_sizes, int n_in,
                              void* d_out, int out_size, void* d_ws, size_t ws_size,
                              hipStream_t stream) {
  const int* features = (const int*)d_in[0];
  float* out = (float*)d_out;
  uint32_t* P = (uint32_t*)d_ws;                    // 16 MB fp4 panel layout
  float* sizes = (float*)((char*)d_ws + (size_t)(B_ROWS / 32) * GBYTES);

  presence_kernel<<<B_ROWS / 4, 256, 0, stream>>>(features, P, sizes);
  gemm_kernel<<<528, 256, 0, stream>>>((const unsigned char*)P, sizes, out);
}

// Round 14
// 166.355 us; speedup vs baseline: 2.3484x; 2.3484x over previous
//
#include <hip/hip_runtime.h>
#include <stdint.h>

#define B_ROWS 4096
#define L_FEAT 256
#define VOCAB  8192
#define FRAG   1024             // one MFMA operand fragment: 32 rows x 64 elems
#define KCHUNKS (VOCAB / 64)    // 128 fragments along K per 32-row group
#define GBYTES  (KCHUNKS * FRAG)   // 128 KB per 32-row group (one copy)
#define PSTRIDE (2 * GBYTES)       // group stride: panel stored TWICE back-to-back
#define NSTEP  128              // K steps of 64 elems

typedef __attribute__((ext_vector_type(4)))  int   intx4;
typedef __attribute__((ext_vector_type(8)))  int   intx8;
typedef __attribute__((ext_vector_type(4)))  float floatx4;
typedef __attribute__((ext_vector_type(16))) float floatx16;

// fp4 operand: HW reads only v[0:3] of the 8-reg A/B field (FMT=4); upper
// half undef (verified r9-r12: passed, absmax 0).
__device__ __forceinline__ intx8 widen(intx4 v) {
  return __builtin_shufflevector(v, v, 0, 1, 2, 3, -1, -1, -1, -1);
}

// ---------------- kernel 1: presence in PANEL layout, DUPLICATED -------------
// (layout verified rounds 10-12) fragment (g,kc) holds rows [32g,32g+32) x
// k-elems [64kc,64kc+64), byte = g*PSTRIDE + kc*1024 + ((row&31)+32*half)*16.
// Each group's 128 KB panel is written twice (copy2 at +GBYTES) so the gemm
// K-loop can start at any fragment and read 128 KB LINEARLY -- the mod-128
// wrap that spilled r13 is absorbed into the layout.
__global__ __launch_bounds__(256) void presence_kernel(
    const int* __restrict__ f,
    uint32_t* __restrict__ P,     // fp4 presence, panel layout x2 (32 MB)
    float* __restrict__ sizes) {
  __shared__ uint32_t rw[4][VOCAB / 8];   // 4 x 1024 words = 16 KB
  const int rbase = blockIdx.x * 4;
  const int tid = threadIdx.x;

  uint4* rp4 = (uint4*)&rw[0][0];         // 1024 uint4
  const uint4 z = make_uint4(0u, 0u, 0u, 0u);
  #pragma unroll
  for (int j = 0; j < 4; ++j) rp4[tid + j * 256] = z;
  __syncthreads();

  #pragma unroll
  for (int r = 0; r < 4; ++r) {
    const int v = f[(rbase + r) * L_FEAT + tid];     // coalesced
    atomicOr(&rw[r][v >> 3], 0x2u << ((v & 7) * 4)); // fp4 nibble 1.0; dups ok
  }
  __syncthreads();

  // panel write: 1024 chunks of 16B; chunk c -> kc=c>>3, half=(c>>2)&1, ro=c&3
  const int g = blockIdx.x >> 3;
  const int slotBase = (blockIdx.x & 7) * 4;   // row slot within 32-row group
  char* Pg = (char*)P + (size_t)g * PSTRIDE;
  #pragma unroll
  for (int j = 0; j < 4; ++j) {
    const int c  = tid + j * 256;
    const int kc = c >> 3, h = (c >> 2) & 1, ro = c & 3;
    const uint4 val = *(const uint4*)&rw[ro][kc * 8 + h * 4];
    const size_t off = (size_t)kc * FRAG + (slotBase + ro + 32 * h) * 16;
    *(uint4*)(Pg + off) = val;             // copy 1
    *(uint4*)(Pg + GBYTES + off) = val;    // copy 2 (enables wrap-free K-phase)
  }

  // sizes: wave w popcounts row w
  const int w = tid >> 6, lane = tid & 63;
  const uint4* sp4 = (const uint4*)&rw[w][0];        // 256 uint4
  int cnt = 0;
  #pragma unroll
  for (int q = 0; q < 4; ++q) {
    const uint4 x = sp4[lane + q * 64];
    cnt += __popc(x.x & 0x22222222u) + __popc(x.y & 0x22222222u) +
           __popc(x.z & 0x22222222u) + __popc(x.w & 0x22222222u);
  }
  #pragma unroll
  for (int off = 32; off > 0; off >>= 1) cnt += __shfl_down(cnt, off);
  if (lane == 0) sizes[rbase + w] = (float)cnt;
}

// ---------------- kernel 2: inter = P·P^T (fp4 MX MFMA) + Jaccard + mirror ---
// Round-14 = round-11's VERIFIED loop (bit-identical structure: reg ring-8,
// linear pointers, no branches) + K-phased start via duplicated panels:
//   kstart = (blockIdx.x & 7) * 16 fragments; blocks on one physical XCD all
//   read the same rotating 2 MB K-slice (128 groups x 16 frags) < 4 MB L2 ->
//   operand delivery moves off the measured ~10.5-11 TB/s L3/fabric ceiling
//   (r10/r11/r12 invariant) onto the L2 tier. r13 tested this but spilled
//   (mid-loop wrap branch, VGPR 128, WRITE 665 MB); the duplicated layout
//   removes the branch so codegen matches r11 (VGPR 116, no spill).
__global__ __launch_bounds__(256, 2) void gemm_kernel(
    const unsigned char* __restrict__ P,
    const float* __restrict__ sizes,
    float* __restrict__ out) {
  // K-phase by PHYSICAL XCD (raw blockIdx, before the swizzle)
  const size_t kstart = (size_t)(blockIdx.x & 7) * 16 * FRAG;

  // XCD swizzle (528 = 8*66 -> bijective)
  int bid = blockIdx.x;
  bid = (bid & 7) * 66 + (bid >> 3);
  // supertile-triangle decode: 8x8 supertiles of 4x4 blocks, bx >= by
  int b = bid, sy = 0, rem = 122;               // 10 + 16*7
  while (b >= rem) { b -= rem; ++sy; rem -= 16; }
  int by, bx;
  if (b < 10) {                                 // diagonal supertile interior
    int ly = 0, r2 = 4;
    while (b >= r2) { b -= r2; ++ly; --r2; }
    by = sy * 4 + ly; bx = sy * 4 + ly + b;
  } else {
    const int t = b - 10;
    const int sx = sy + 1 + (t >> 4);
    const int l = t & 15;
    by = sy * 4 + (l >> 2); bx = sx * 4 + (l & 3);
  }

  const int tid  = threadIdx.x;
  const int wave = tid >> 6, lane = tid & 63;
  const int wm = wave >> 1, wn = wave & 1;   // 2x2 wave grid, each wave 64x64
  const int r31 = lane & 31, khalf = lane >> 5;

  const int iB = by * 128 + wm * 64;   // this wave's output rows
  const int jB = bx * 128 + wn * 64;   // this wave's output cols

  // fragment base pointers: phase-offset start, 128 frags read LINEARLY
  // (max end = 112 KB + 128 KB = 240 KB < PSTRIDE: always in-bounds)
  const unsigned char* pA0 =
      P + (size_t)(by * 4 + wm * 2 + 0) * PSTRIDE + kstart + lane * 16;
  const unsigned char* pA1 =
      P + (size_t)(by * 4 + wm * 2 + 1) * PSTRIDE + kstart + lane * 16;
  const unsigned char* pB0 =
      P + (size_t)(bx * 4 + wn * 2 + 0) * PSTRIDE + kstart + lane * 16;
  const unsigned char* pB1 =
      P + (size_t)(bx * 4 + wn * 2 + 1) * PSTRIDE + kstart + lane * 16;

  floatx16 acc[2][2];
  #pragma unroll
  for (int ai = 0; ai < 2; ++ai)
    #pragma unroll
    for (int ci = 0; ci < 2; ++ci)
      #pragma unroll
      for (int e = 0; e < 16; ++e) acc[ai][ci][e] = 0.f;

  intx4 a0[8], a1[8], b0[8], b1[8];   // 8-step register ring, literal indices

  #pragma unroll
  for (int j = 0; j < 8; ++j) {       // prologue: phase-steps 0..7
    a0[j] = *(const intx4*)(pA0 + j * FRAG);
    a1[j] = *(const intx4*)(pA1 + j * FRAG);
    b0[j] = *(const intx4*)(pB0 + j * FRAG);
    b1[j] = *(const intx4*)(pB1 + j * FRAG);
  }
  pA0 += 8 * FRAG; pA1 += 8 * FRAG; pB0 += 8 * FRAG; pB1 += 8 * FRAG;

  #define STEP(j)                                                             \
    {                                                                         \
      const intx8 A0 = widen(a0[j]), A1 = widen(a1[j]);                       \
      const intx8 B0 = widen(b0[j]), B1 = widen(b1[j]);                       \
      acc[0][0] = __builtin_amdgcn_mfma_scale_f32_32x32x64_f8f6f4(            \
          A0, B0, acc[0][0], 4, 4, 0, 127, 0, 127);                           \
      acc[0][1] = __builtin_amdgcn_mfma_scale_f32_32x32x64_f8f6f4(            \
          A0, B1, acc[0][1], 4, 4, 0, 127, 0, 127);                           \
      acc[1][0] = __builtin_amdgcn_mfma_scale_f32_32x32x64_f8f6f4(            \
          A1, B0, acc[1][0], 4, 4, 0, 127, 0, 127);                           \
      acc[1][1] = __builtin_amdgcn_mfma_scale_f32_32x32x64_f8f6f4(            \
          A1, B1, acc[1][1], 4, 4, 0, 127, 0, 127);                           \
    }
  #define PREF(j)                                                             \
    {                                                                         \
      a0[j] = *(const intx4*)(pA0 + (j) * FRAG);                              \
      a1[j] = *(const intx4*)(pA1 + (j) * FRAG);                              \
      b0[j] = *(const intx4*)(pB0 + (j) * FRAG);                              \
      b1[j] = *(const intx4*)(pB1 + (j) * FRAG);                              \
    }

  // 15 bodies x 8 steps = steps 0..119 consumed, prefetch up to step 127
  for (int i = 0; i < 15; ++i) {
    STEP(0) PREF(0)
    STEP(1) PREF(1)
    STEP(2) PREF(2)
    STEP(3) PREF(3)
    STEP(4) PREF(4)
    STEP(5) PREF(5)
    STEP(6) PREF(6)
    STEP(7) PREF(7)
    pA0 += 8 * FRAG; pA1 += 8 * FRAG; pB0 += 8 * FRAG; pB1 += 8 * FRAG;
  }
  STEP(0) STEP(1) STEP(2) STEP(3)     // steps 120..127
  STEP(4) STEP(5) STEP(6) STEP(7)

  // epilogue (verified rounds 5-12): sim = -inter/(|A_i|+|A_j|-inter) + mirror.
  // 32x32 C layout: col = lane&31, row = (reg&3) + 8*(reg>>2) + 4*(lane>>5).
  #pragma unroll
  for (int tm = 0; tm < 2; ++tm) {
    const int rowb = iB + tm * 32 + 4 * khalf;
    #pragma unroll
    for (int tn = 0; tn < 2; ++tn) {
      const int colb = jB + tn * 32 + r31;
      const float sj = sizes[colb];
      #pragma unroll
      for (int q = 0; q < 4; ++q) {           // reg quads: rows rq..rq+3
        const int rq = rowb + 8 * q;
        floatx4 tv;
        #pragma unroll
        for (int j = 0; j < 4; ++j) {
          const float inter = acc[tm][tn][4 * q + j];
          const float u = sizes[rq + j] + sj - inter;
          tv[j] = (u != 0.f) ? (-inter / u) : 0.f;
        }
        __builtin_nontemporal_store(tv[0], &out[(size_t)(rq + 0) * B_ROWS + colb]);
        __builtin_nontemporal_store(tv[1], &out[(size_t)(rq + 1) * B_ROWS + colb]);
        __builtin_nontemporal_store(tv[2], &out[(size_t)(rq + 2) * B_ROWS + colb]);
        __builtin_nontemporal_store(tv[3], &out[(size_t)(rq + 3) * B_ROWS + colb]);
        // mirrored: 4 row-values contiguous in the transposed row (16B-aligned)
        __builtin_nontemporal_store(tv, (floatx4*)&out[(size_t)colb * B_ROWS + rq]);
      }
    }
  }
}

// ---------------- launcher ---------------------------------------------------
extern "C" void kernel_launch(void* const* d_in, const int* in_sizes, int n_in,
                              void* d_out, int out_size, void* d_ws, size_t ws_size,
                              hipStream_t stream) {
  const int* features = (const int*)d_in[0];
  float* out = (float*)d_out;
  uint32_t* P = (uint32_t*)d_ws;                    // 32 MB fp4 panel layout x2
  float* sizes = (float*)((char*)d_ws + (size_t)(B_ROWS / 32) * PSTRIDE);

  presence_kernel<<<B_ROWS / 4, 256, 0, stream>>>(features, P, sizes);
  gemm_kernel<<<528, 256, 0, stream>>>((const unsigned char*)P, sizes, out);
}